// Round 1
// 205.371 us; speedup vs baseline: 1.0800x; 1.0800x over previous
//
#include <hip/hip_runtime.h>
#include <hip/hip_bf16.h>

// GATv2 x2 on MI355X — R22: decoupled index loads + deep row prefetch in
//  k_node1f. Evidence (R21 rocprof): k_node1f 62.4us, VALUBusy 52%,
//  hbm 25%, MfmaUtil 0 — latency-bound. Root cause: per-edge dependent
//  chain idx=sp[i] (VMEM) -> row=xl1b[idx] forces an effective vmcnt(0)
//  every iteration (in-order vmcnt), draining the row prefetch pipeline.
//  Fix: one 64-wide index batch load per node + __shfl (ds_bpermute,
//  lgkmcnt path) extraction; rows are now the only vmcnt traffic, kept
//  4-8 deep via a 4-edge unrolled body with named buffers.
//  Numerics identical (same ops, same order) -> absmax must stay 0.015625.
//  All other kernels unchanged from R21.

constexpr int N_NODES = 10000;
constexpr int N_EDGES = 320000;
constexpr int ET      = N_EDGES + N_NODES;   // 330000 incl. self loops
constexpr float NEG_SLOPE = 0.2f;

constexpr int NB_COUNT  = (ET + 255) / 256;          // 1290
constexpr int NB_CONVX  = (N_NODES * 64) / 256;      // 2500
constexpr int NB_CONVW  = (1024 * 64) / 256;         // 256
constexpr int NB_CONVW2 = (64 * 128) / 256;          // 32

typedef __attribute__((ext_vector_type(8))) short short8;
typedef __attribute__((ext_vector_type(8))) unsigned short ushort8_t;
typedef __attribute__((ext_vector_type(4))) float floatx4;

__device__ __forceinline__ float lrelu(float a) {
    return fmaxf(a, NEG_SLOPE * a);
}
__device__ __forceinline__ unsigned short f2bf(float f) {   // RNE
    unsigned u = __float_as_uint(f);
    unsigned r = u + 0x7FFFu + ((u >> 16) & 1u);
    return (unsigned short)(r >> 16);
}
__device__ __forceinline__ float bf2f(unsigned short h) {
    return __uint_as_float((unsigned)h << 16);
}
// sum over each aligned group of 8 lanes, result in all 8 (pure VALU)
__device__ __forceinline__ float red8_dpp(float p) {
    int x;
    x = __builtin_amdgcn_update_dpp(0, __float_as_int(p), 0xB1, 0xF, 0xF, true);
    p += __int_as_float(x);                  // quad_perm [1,0,3,2]
    x = __builtin_amdgcn_update_dpp(0, __float_as_int(p), 0x4E, 0xF, 0xF, true);
    p += __int_as_float(x);                  // quad_perm [2,3,0,1]
    x = __builtin_amdgcn_update_dpp(0, __float_as_int(p), 0x141, 0xF, 0xF, true);
    p += __int_as_float(x);                  // row_half_mirror
    return p;
}
__device__ __forceinline__ float red8max_dpp(float p) {
    int x;
    x = __builtin_amdgcn_update_dpp(0, __float_as_int(p), 0xB1, 0xF, 0xF, true);
    p = fmaxf(p, __int_as_float(x));
    x = __builtin_amdgcn_update_dpp(0, __float_as_int(p), 0x4E, 0xF, 0xF, true);
    p = fmaxf(p, __int_as_float(x));
    x = __builtin_amdgcn_update_dpp(0, __float_as_int(p), 0x141, 0xF, 0xF, true);
    p = fmaxf(p, __int_as_float(x));
    return p;
}
// pairwise add with lane^8 partner (row_ror:8 within 16-lane rows)
__device__ __forceinline__ float ror8_add(float p) {
    int x = __builtin_amdgcn_update_dpp(0, __float_as_int(p), 0x128, 0xF, 0xF, true);
    return p + __int_as_float(x);
}

// ------- fused prep: deg count + conv_x + conv_w1 + conv_w2 -------

__global__ __launch_bounds__(256) void k_prep(const int* __restrict__ ei,
        int* __restrict__ deg, const float* __restrict__ x,
        unsigned short* __restrict__ A, const float* __restrict__ Wl,
        const float* __restrict__ Wr, unsigned short* __restrict__ Bt,
        const float* __restrict__ W2l, const float* __restrict__ W2r,
        unsigned short* __restrict__ Bt2) {
    int b = blockIdx.x, t = threadIdx.x;
    if (b < NB_COUNT) {
        int e = b * 256 + t;
        if (e >= ET) return;
        int d = (e < N_EDGES) ? ei[N_EDGES + e] : (e - N_EDGES);
        atomicAdd(&deg[d], 1);
    } else if (b < NB_COUNT + NB_CONVX) {
        int idx = (b - NB_COUNT) * 256 + t;       // < N_NODES*64
        int m = idx >> 6, kg = (idx & 63) << 2;
        float4 v = *reinterpret_cast<const float4*>(x + (size_t)m * 256 + kg);
        ushort4 hi = make_ushort4(f2bf(v.x), f2bf(v.y), f2bf(v.z), f2bf(v.w));
        *reinterpret_cast<ushort4*>(A + (size_t)m * 256 + kg) = hi;
    } else if (b < NB_COUNT + NB_CONVX + NB_CONVW) {
        int idx = (b - NB_COUNT - NB_CONVX) * 256 + t;   // < 1024*64
        int n = idx >> 6, kg = (idx & 63) << 2;
        const float* src = (n < 512) ? (Wl + n) : (Wr + (n - 512));
        float v0 = src[(size_t)(kg + 0) * 512];
        float v1 = src[(size_t)(kg + 1) * 512];
        float v2 = src[(size_t)(kg + 2) * 512];
        float v3 = src[(size_t)(kg + 3) * 512];
        ushort4 hi = make_ushort4(f2bf(v0), f2bf(v1), f2bf(v2), f2bf(v3));
        *reinterpret_cast<ushort4*>(Bt + (size_t)n * 256 + kg) = hi;
    } else {
        int idx = (b - NB_COUNT - NB_CONVX - NB_CONVW) * 256 + t;  // < 64*128
        int j = idx >> 7, kg = (idx & 127) << 2;
        const float* src = (j < 32) ? (W2l + j) : (W2r + (j - 32));
        float v0 = src[(size_t)(kg + 0) * 32];
        float v1 = src[(size_t)(kg + 1) * 32];
        float v2 = src[(size_t)(kg + 2) * 32];
        float v3 = src[(size_t)(kg + 3) * 32];
        ushort4 hi = make_ushort4(f2bf(v0), f2bf(v1), f2bf(v2), f2bf(v3));
        *reinterpret_cast<ushort4*>(Bt2 + (size_t)j * 512 + kg) = hi;
    }
}

// ---------------- CSR scan + scatter ----------------

__global__ __launch_bounds__(1024) void k_scan(const int* __restrict__ deg,
                                               int* __restrict__ offs) {
    __shared__ int part[1024];
    const int CH = 10;                       // ceil(10000/1024)
    int t = threadIdx.x;
    int base = t * CH;
    int loc[CH];
    int s = 0;
    for (int i = 0; i < CH; ++i) {
        int idx = base + i;
        int v = (idx < N_NODES) ? deg[idx] : 0;
        loc[i] = s; s += v;
    }
    part[t] = s;
    __syncthreads();
    for (int o = 1; o < 1024; o <<= 1) {
        int add = (t >= o) ? part[t - o] : 0;
        __syncthreads();
        part[t] += add;
        __syncthreads();
    }
    int excl = part[t] - s;
    for (int i = 0; i < CH; ++i) {
        int idx = base + i;
        if (idx < N_NODES) offs[idx] = excl + loc[i];
    }
    if (t == 1023) offs[N_NODES] = part[1023];
}

// deg doubles as countdown cursor: pos = offs[d] + (--deg[d])
__global__ void k_scatter(const int* __restrict__ ei, const int* __restrict__ offs,
                          int* __restrict__ deg, int* __restrict__ ssrc) {
    int e = blockIdx.x * 256 + threadIdx.x;
    if (e >= ET) return;
    int s, d;
    if (e < N_EDGES) { s = ei[e]; d = ei[N_EDGES + e]; }
    else             { s = d = e - N_EDGES; }
    int pos = offs[d] + atomicAdd(&deg[d], -1) - 1;
    ssrc[pos] = s;
}

// ---------------- layer 1 MFMA GEMM ----------------

// 128x128 tile, M=10000 N=1024 K=256 (pure bf16), grid (79,8), 4 waves/block.
__global__ __launch_bounds__(256) void k_mfma1(const unsigned short* __restrict__ A,
        const unsigned short* __restrict__ Bt, unsigned short* __restrict__ xl1b,
        unsigned short* __restrict__ xr1b) {
    __shared__ unsigned short As[128 * 40];   // stride 40: 2-way max = free
    __shared__ unsigned short Bs[128 * 40];
    int t = threadIdx.x;
    int wave = t >> 6, L = t & 63;
    int wm = wave & 1, wn = wave >> 1;
    int row0 = blockIdx.x * 128, n0 = blockIdx.y * 128;
    int q = L >> 4, rr = L & 15;
    floatx4 acc[4][4];
#pragma unroll
    for (int i = 0; i < 4; ++i)
#pragma unroll
        for (int j = 0; j < 4; ++j) acc[i][j] = (floatx4){0.f, 0.f, 0.f, 0.f};
    int ra = t >> 2,        ka = (t & 3) * 8;
    int rb = (t + 256) >> 2, kb = ((t + 256) & 3) * 8;
    int gma = row0 + ra; gma = (gma < N_NODES) ? gma : (N_NODES - 1);
    int gmb = row0 + rb; gmb = (gmb < N_NODES) ? gmb : (N_NODES - 1);
    for (int kc = 0; kc < 256; kc += 32) {
        __syncthreads();
        *reinterpret_cast<uint4*>(&As[ra * 40 + ka]) =
            *reinterpret_cast<const uint4*>(A + (size_t)gma * 256 + kc + ka);
        *reinterpret_cast<uint4*>(&As[rb * 40 + kb]) =
            *reinterpret_cast<const uint4*>(A + (size_t)gmb * 256 + kc + kb);
        *reinterpret_cast<uint4*>(&Bs[ra * 40 + ka]) =
            *reinterpret_cast<const uint4*>(Bt + (size_t)(n0 + ra) * 256 + kc + ka);
        *reinterpret_cast<uint4*>(&Bs[rb * 40 + kb]) =
            *reinterpret_cast<const uint4*>(Bt + (size_t)(n0 + rb) * 256 + kc + kb);
        __syncthreads();
        short8 af[4], bf[4];
#pragma unroll
        for (int st = 0; st < 4; ++st)
            af[st] = *reinterpret_cast<const short8*>(
                &As[(wm * 64 + st * 16 + rr) * 40 + q * 8]);
#pragma unroll
        for (int st = 0; st < 4; ++st)
            bf[st] = *reinterpret_cast<const short8*>(
                &Bs[(wn * 64 + st * 16 + rr) * 40 + q * 8]);
#pragma unroll
        for (int i = 0; i < 4; ++i)
#pragma unroll
            for (int j = 0; j < 4; ++j)
                acc[i][j] = __builtin_amdgcn_mfma_f32_16x16x32_bf16(
                    af[i], bf[j], acc[i][j], 0, 0, 0);
    }
    // epilogue: C/D layout col=lane&15, row=(lane>>4)*4+reg  [m89/m91]
#pragma unroll
    for (int j = 0; j < 4; ++j) {
        int gc = n0 + wn * 64 + j * 16 + rr;
        unsigned short* dst = (gc < 512) ? xl1b : xr1b;
        int col = (gc < 512) ? gc : (gc - 512);
#pragma unroll
        for (int i = 0; i < 4; ++i)
#pragma unroll
            for (int r = 0; r < 4; ++r) {
                int gr = row0 + wm * 64 + i * 16 + q * 4 + r;
                if (gr < N_NODES)
                    dst[(size_t)gr * 512 + col] = f2bf(acc[i][j][r]);
            }
    }
}

// Fused edge+node layer 1 — wave = node (block = 4 nodes, barrier-free).
// R22: indices for the whole node are fetched in ONE 64-wide VMEM load and
// broadcast per-edge via __shfl (ds_bpermute -> lgkmcnt, NOT vmcnt), so the
// only vmcnt traffic is the 1KB row gathers, software-pipelined 4-8 deep
// in a 4-edge unrolled body (named buffers: no runtime-indexed arrays).
__global__ __launch_bounds__(256) void k_node1f(const int* __restrict__ offs,
        const int* __restrict__ ssrc, const unsigned short* __restrict__ xl1b,
        const unsigned short* __restrict__ xr1b, const float* __restrict__ att1,
        const float* __restrict__ b1, unsigned short* __restrict__ h1b) {
    int t = threadIdx.x;
    int wave = t >> 6, lane = t & 63;
    int n = blockIdx.x * 4 + wave;
    if (n >= N_NODES) return;
    int beg = offs[n], dcnt = offs[n + 1] - beg;
    float xrv[8], atv[8];
    {
        ushort8_t xru = *reinterpret_cast<const ushort8_t*>(
            xr1b + (size_t)n * 512 + lane * 8);
        const float* atrow = att1 + lane * 8;
        float4 c0 = *reinterpret_cast<const float4*>(atrow);
        float4 c1 = *reinterpret_cast<const float4*>(atrow + 4);
#pragma unroll
        for (int i = 0; i < 8; ++i) xrv[i] = bf2f(xru[i]);
        atv[0]=c0.x; atv[1]=c0.y; atv[2]=c0.z; atv[3]=c0.w;
        atv[4]=c1.x; atv[5]=c1.y; atv[6]=c1.z; atv[7]=c1.w;
    }
    float l = 0.f;
    float acc8[8];
#pragma unroll
    for (int i = 0; i < 8; ++i) acc8[i] = 0.f;
    const int* sp = ssrc + beg;
    const char* xlbase = reinterpret_cast<const char*>(xl1b) + lane * 16;
    auto ld_row = [&](int off) -> ushort8_t {
        return *reinterpret_cast<const ushort8_t*>(xlbase + off);
    };
    for (int b0 = 0; b0 < dcnt; b0 += 64) {
        int bn = dcnt - b0; if (bn > 64) bn = 64;
        // one batched index load per 64 edges (clamped; bn >= 1 always)
        int idxv = sp[b0 + ((lane < bn) ? lane : (bn - 1))];
        auto off_at = [&](int k) -> int {
            int kc = (k < bn) ? k : (bn - 1);
            return __shfl(idxv, kc, 64) << 10;   // ds_bpermute: lgkmcnt path
        };
        // per-edge compute; idx >= bn contributes 0 (tail mask)
        auto edge = [&](ushort8_t u, int idx) {
            float xs[8];
#pragma unroll
            for (int j = 0; j < 8; ++j) xs[j] = bf2f(u[j]);
            float p0 = 0.f, p1 = 0.f;
#pragma unroll
            for (int j = 0; j < 4; ++j) {
                p0 += lrelu(xs[j] + xrv[j]) * atv[j];
                p1 += lrelu(xs[j + 4] + xrv[j + 4]) * atv[j + 4];
            }
            float p = red8_dpp(p0 + p1);        // alpha for this lane's head
            float w = __expf(fminf(p, 60.f));
            if (idx >= bn) w = 0.f;
            l += w;
#pragma unroll
            for (int j = 0; j < 8; ++j) acc8[j] += w * xs[j];
        };
        ushort8_t u0 = ld_row(off_at(0));
        ushort8_t u1 = ld_row(off_at(1));
        ushort8_t u2 = ld_row(off_at(2));
        ushort8_t u3 = ld_row(off_at(3));
        for (int i = 0; i < bn; i += 4) {
            ushort8_t n0 = ld_row(off_at(i + 4));   // prefetch next block
            ushort8_t n1 = ld_row(off_at(i + 5));
            ushort8_t n2 = ld_row(off_at(i + 6));
            ushort8_t n3 = ld_row(off_at(i + 7));
            edge(u0, i);
            edge(u1, i + 1);
            edge(u2, i + 2);
            edge(u3, i + 3);
            u0 = n0; u1 = n1; u2 = n2; u3 = n3;
        }
    }
    float inv = 1.f / (l + 1e-16f);
    const float* brow = b1 + lane * 8;
    ushort8_t vout;
#pragma unroll
    for (int j = 0; j < 8; ++j) {
        float v = acc8[j] * inv + brow[j];
        v = (v > 0.f) ? v : (__expf(v) - 1.f);  // elu (fast exp)
        vout[j] = f2bf(v);
    }
    *reinterpret_cast<ushort8_t*>(h1b + (size_t)n * 512 + lane * 8) = vout;
}

// ---------------- layer 2: MFMA GEMM ----------------

// M=10000, N=64, K=512 bf16. 64-row tiles, 4 waves (wave = 16 rows).
__global__ __launch_bounds__(256) void k_mfma2(const unsigned short* __restrict__ h1b,
        const unsigned short* __restrict__ Bt2, float* __restrict__ xw2) {
    __shared__ unsigned short Hs[64 * 40];
    __shared__ unsigned short Ws[64 * 40];
    int t = threadIdx.x;
    int wave = t >> 6, L = t & 63;
    int row0 = blockIdx.x * 64;
    int q = L >> 4, rr = L & 15;
    floatx4 acc[4];
#pragma unroll
    for (int j = 0; j < 4; ++j) acc[j] = (floatx4){0.f, 0.f, 0.f, 0.f};
    int ra = t >> 2, ka = (t & 3) * 8;       // 64 rows x 4 chunks = 1/thread
    int gma = row0 + ra; gma = (gma < N_NODES) ? gma : (N_NODES - 1);
    for (int kc = 0; kc < 512; kc += 32) {
        __syncthreads();
        *reinterpret_cast<uint4*>(&Hs[ra * 40 + ka]) =
            *reinterpret_cast<const uint4*>(h1b + (size_t)gma * 512 + kc + ka);
        *reinterpret_cast<uint4*>(&Ws[ra * 40 + ka]) =
            *reinterpret_cast<const uint4*>(Bt2 + (size_t)ra * 512 + kc + ka);
        __syncthreads();
        short8 af = *reinterpret_cast<const short8*>(
            &Hs[(wave * 16 + rr) * 40 + q * 8]);
#pragma unroll
        for (int j = 0; j < 4; ++j) {
            short8 bf = *reinterpret_cast<const short8*>(
                &Ws[(j * 16 + rr) * 40 + q * 8]);
            acc[j] = __builtin_amdgcn_mfma_f32_16x16x32_bf16(af, bf, acc[j], 0, 0, 0);
        }
    }
    // epilogue: col=lane&15, row=(lane>>4)*4+reg
#pragma unroll
    for (int j = 0; j < 4; ++j) {
        int gc = j * 16 + rr;
#pragma unroll
        for (int r = 0; r < 4; ++r) {
            int gr = row0 + wave * 16 + q * 4 + r;
            if (gr < N_NODES) xw2[(size_t)gr * 64 + gc] = acc[j][r];
        }
    }
}

// Fused edge+node layer 2 + log_softmax: block = 4 nodes, wave = node,
// barrier-free. Full-chunk loop + masked tail. (xw2 is 2.5 MB, L2-hot.)
__global__ __launch_bounds__(256) void k_node2f(const int* __restrict__ offs,
        const int* __restrict__ ssrc, const float* __restrict__ xw2,
        const float* __restrict__ att2, const float* __restrict__ b2,
        float* __restrict__ out) {
    int t = threadIdx.x;
    int wave = t >> 6, lane = t & 63;
    int n = blockIdx.x * 4 + wave;
    if (n >= N_NODES) return;
    int ej = lane >> 3;
    int cg = lane & 7;
    int beg = offs[n], dcnt = offs[n + 1] - beg;
    float4 xr = *reinterpret_cast<const float4*>(
                    xw2 + (size_t)n * 64 + 32 + cg * 4);
    float4 at = *reinterpret_cast<const float4*>(att2 + cg * 4);
    float l = 0.f;
    float4 ac = {0.f, 0.f, 0.f, 0.f};
    const int* sp = ssrc + beg;
    const char* xwbase = reinterpret_cast<const char*>(xw2) + cg * 16;
    auto ld_off = [&](int i1) -> int {
        int i1c = (i1 < dcnt) ? i1 : (dcnt - 1);
        return sp[i1c] << 8;
    };
    auto ld_row = [&](int off) -> float4 {
        return *reinterpret_cast<const float4*>(xwbase + off);
    };
    int full = dcnt & ~15;
    float4 uA = ld_row(ld_off(ej));
    float4 uB = ld_row(ld_off(8 + ej));
    int oA1 = ld_off(16 + ej), oB1 = ld_off(24 + ej);
    for (int base = 0; base < full; base += 16) {
        float4 uA1 = ld_row(oA1), uB1 = ld_row(oB1);
        int oA2 = ld_off(base + 32 + ej);
        int oB2 = ld_off(base + 40 + ej);
        float pA0 = lrelu(uA.x + xr.x) * at.x + lrelu(uA.z + xr.z) * at.z;
        float pA1 = lrelu(uA.y + xr.y) * at.y + lrelu(uA.w + xr.w) * at.w;
        float pB0 = lrelu(uB.x + xr.x) * at.x + lrelu(uB.z + xr.z) * at.z;
        float pB1 = lrelu(uB.y + xr.y) * at.y + lrelu(uB.w + xr.w) * at.w;
        float wA = __expf(fminf(red8_dpp(pA0 + pA1), 60.f));
        float wB = __expf(fminf(red8_dpp(pB0 + pB1), 60.f));
        l += wA + wB;
        ac.x += wA * uA.x + wB * uB.x;
        ac.y += wA * uA.y + wB * uB.y;
        ac.z += wA * uA.z + wB * uB.z;
        ac.w += wA * uA.w + wB * uB.w;
        uA = uA1; uB = uB1; oA1 = oA2; oB1 = oB2;
    }
    if (full < dcnt) {
        float pA0 = lrelu(uA.x + xr.x) * at.x + lrelu(uA.z + xr.z) * at.z;
        float pA1 = lrelu(uA.y + xr.y) * at.y + lrelu(uA.w + xr.w) * at.w;
        float pB0 = lrelu(uB.x + xr.x) * at.x + lrelu(uB.z + xr.z) * at.z;
        float pB1 = lrelu(uB.y + xr.y) * at.y + lrelu(uB.w + xr.w) * at.w;
        float pA = red8_dpp(pA0 + pA1);
        float pB = red8_dpp(pB0 + pB1);
        if (full + ej >= dcnt)     pA = -1e30f;
        if (full + 8 + ej >= dcnt) pB = -1e30f;
        float wA = __expf(fminf(pA, 60.f));
        float wB = __expf(fminf(pB, 60.f));
        l += wA + wB;
        ac.x += wA * uA.x + wB * uB.x;
        ac.y += wA * uA.y + wB * uB.y;
        ac.z += wA * uA.z + wB * uB.z;
        ac.w += wA * uA.w + wB * uB.w;
    }
    l = ror8_add(l); l += __shfl_xor(l, 16); l += __shfl_xor(l, 32);
    ac.x = ror8_add(ac.x); ac.x += __shfl_xor(ac.x, 16); ac.x += __shfl_xor(ac.x, 32);
    ac.y = ror8_add(ac.y); ac.y += __shfl_xor(ac.y, 16); ac.y += __shfl_xor(ac.y, 32);
    ac.z = ror8_add(ac.z); ac.z += __shfl_xor(ac.z, 16); ac.z += __shfl_xor(ac.z, 32);
    ac.w = ror8_add(ac.w); ac.w += __shfl_xor(ac.w, 16); ac.w += __shfl_xor(ac.w, 32);
    float inv = 1.f / (l + 1e-16f);
    float4 bb = *reinterpret_cast<const float4*>(b2 + cg * 4);
    float4 v;
    v.x = ac.x * inv + bb.x; v.y = ac.y * inv + bb.y;
    v.z = ac.z * inv + bb.z; v.w = ac.w * inv + bb.w;
    // log_softmax over 32 channels (8-lane DPP; ej groups identical)
    float mx = red8max_dpp(fmaxf(fmaxf(v.x, v.y), fmaxf(v.z, v.w)));
    float se = red8_dpp(__expf(v.x - mx) + __expf(v.y - mx)
                      + __expf(v.z - mx) + __expf(v.w - mx));
    float ls = __logf(se);
    v.x = v.x - mx - ls; v.y = v.y - mx - ls;
    v.z = v.z - mx - ls; v.w = v.w - mx - ls;
    if (ej == 0)
        *reinterpret_cast<float4*>(out + (size_t)n * 32 + cg * 4) = v;
}

// ---------------- launch ----------------

extern "C" void kernel_launch(void* const* d_in, const int* in_sizes, int n_in,
                              void* d_out, int out_size, void* d_ws, size_t ws_size,
                              hipStream_t stream) {
    (void)in_sizes; (void)n_in; (void)out_size; (void)ws_size;
    const float* x    = (const float*)d_in[0];
    const int*   ei   = (const int*)d_in[1];
    const float* W1l  = (const float*)d_in[2];
    const float* W1r  = (const float*)d_in[3];
    const float* att1 = (const float*)d_in[4];
    const float* b1   = (const float*)d_in[5];
    const float* W2l  = (const float*)d_in[6];
    const float* W2r  = (const float*)d_in[7];
    const float* att2 = (const float*)d_in[8];
    const float* b2   = (const float*)d_in[9];
    float* outp = (float*)d_out;

    char* ws = (char*)d_ws;
    size_t o = 0;
    auto alloc = [&](size_t bytes) {
        char* p = ws + o;
        o = (o + bytes + 255) & ~(size_t)255;
        return p;
    };
    unsigned short* xl1b = (unsigned short*)alloc((size_t)N_NODES * 512 * 2);
    unsigned short* xr1b = (unsigned short*)alloc((size_t)N_NODES * 512 * 2);
    unsigned short* h1b  = (unsigned short*)alloc((size_t)N_NODES * 512 * 2);
    float* xw2    = (float*)alloc((size_t)N_NODES * 64 * 4);
    unsigned short* Abf = (unsigned short*)alloc((size_t)N_NODES * 256 * 2);
    unsigned short* Bbf = (unsigned short*)alloc((size_t)1024 * 256 * 2);
    unsigned short* Bt2 = (unsigned short*)alloc((size_t)64 * 512 * 2);
    int*   deg    = (int*)alloc((size_t)N_NODES * 4);
    int*   offs   = (int*)alloc((size_t)(N_NODES + 1) * 4);
    int*   ssrc   = (int*)alloc((size_t)ET * 4);

    hipMemsetAsync(deg, 0, (size_t)N_NODES * 4, stream);

    k_prep   <<<NB_COUNT + NB_CONVX + NB_CONVW + NB_CONVW2, 256, 0, stream>>>(
                 ei, deg, x, Abf, W1l, W1r, Bbf, W2l, W2r, Bt2);
    k_scan   <<<1,                    1024, 0, stream>>>(deg, offs);
    k_scatter<<<(ET + 255) / 256,      256, 0, stream>>>(ei, offs, deg, ssrc);
    k_mfma1  <<<dim3(79, 8),           256, 0, stream>>>(Abf, Bbf, xl1b, xr1b);
    k_node1f <<<(N_NODES + 3) / 4,     256, 0, stream>>>(offs, ssrc, xl1b, xr1b, att1, b1, h1b);
    k_mfma2  <<<(N_NODES + 63) / 64,   256, 0, stream>>>(h1b, Bt2, xw2);
    k_node2f <<<(N_NODES + 3) / 4,     256, 0, stream>>>(offs, ssrc, xw2, att2, b2, outp);
}

// Round 2
// 201.858 us; speedup vs baseline: 1.0988x; 1.0174x over previous
//
#include <hip/hip_runtime.h>
#include <hip/hip_bf16.h>

// GATv2 x2 on MI355X — R23:
//  (1) k_node1f: packed-f32 math (v_pk_add/fma_f32) via lrelu identity
//      lrelu(y)=0.6y+0.4|y|  ->  p = pk_dot(0.6at,xs) + K0 + pk_dot(0.4at,|xs+xr|),
//      K0 hoisted per node; message accumulate in pk_fma. ~62 -> ~48 VALU/edge.
//  (2) k_node1f: 2 waves per node (block = 2 nodes) + LDS combine: 2x resident
//      waves, half the serial chain and high-degree tail. Evidence: R22 counters
//      VALUBusy 70% / occupancy 28% -> mixed VALU+latency regime.
//  (3) k_node2f: same batched-index fix proven in R22 for node1f (remove
//      dependent sp[] loads from the vmcnt stream) + depth-2 row pipeline.
//  (4) fuse k_scatter into k_mfma1 launch (blockIdx-partitioned): one fewer
//      launch gap; memory-bound scatter overlaps compute-bound GEMM.

constexpr int N_NODES = 10000;
constexpr int N_EDGES = 320000;
constexpr int ET      = N_EDGES + N_NODES;   // 330000 incl. self loops
constexpr float NEG_SLOPE = 0.2f;

constexpr int NB_COUNT  = (ET + 255) / 256;          // 1290
constexpr int NB_CONVX  = (N_NODES * 64) / 256;      // 2500
constexpr int NB_CONVW  = (1024 * 64) / 256;         // 256
constexpr int NB_CONVW2 = (64 * 128) / 256;          // 32
constexpr int NB_M1     = 79 * 8;                    // mfma1 tiles

typedef __attribute__((ext_vector_type(8))) short short8;
typedef __attribute__((ext_vector_type(8))) unsigned short ushort8_t;
typedef __attribute__((ext_vector_type(4))) float floatx4;
typedef __attribute__((ext_vector_type(2))) float floatx2;

__device__ __forceinline__ float lrelu(float a) {
    return fmaxf(a, NEG_SLOPE * a);
}
__device__ __forceinline__ unsigned short f2bf(float f) {   // RNE
    unsigned u = __float_as_uint(f);
    unsigned r = u + 0x7FFFu + ((u >> 16) & 1u);
    return (unsigned short)(r >> 16);
}
__device__ __forceinline__ float bf2f(unsigned short h) {
    return __uint_as_float((unsigned)h << 16);
}
// packed f32 (VOP3P, gfx90a+): 2 channels per instruction
__device__ __forceinline__ floatx2 pk_add(floatx2 a, floatx2 b) {
    floatx2 d;
    asm("v_pk_add_f32 %0, %1, %2" : "=v"(d) : "v"(a), "v"(b));
    return d;
}
__device__ __forceinline__ floatx2 pk_fma(floatx2 a, floatx2 b, floatx2 c) {
    floatx2 d;
    asm("v_pk_fma_f32 %0, %1, %2, %3" : "=v"(d) : "v"(a), "v"(b), "v"(c));
    return d;
}
// two bf16 packed in a u32 -> floatx2 {lo, hi}
__device__ __forceinline__ floatx2 unpk(unsigned w) {
    floatx2 r;
    r.x = __uint_as_float(w << 16);
    r.y = __uint_as_float(w & 0xffff0000u);
    return r;
}
// sum over each aligned group of 8 lanes, result in all 8 (pure VALU)
__device__ __forceinline__ float red8_dpp(float p) {
    int x;
    x = __builtin_amdgcn_update_dpp(0, __float_as_int(p), 0xB1, 0xF, 0xF, true);
    p += __int_as_float(x);                  // quad_perm [1,0,3,2]
    x = __builtin_amdgcn_update_dpp(0, __float_as_int(p), 0x4E, 0xF, 0xF, true);
    p += __int_as_float(x);                  // quad_perm [2,3,0,1]
    x = __builtin_amdgcn_update_dpp(0, __float_as_int(p), 0x141, 0xF, 0xF, true);
    p += __int_as_float(x);                  // row_half_mirror
    return p;
}
__device__ __forceinline__ float red8max_dpp(float p) {
    int x;
    x = __builtin_amdgcn_update_dpp(0, __float_as_int(p), 0xB1, 0xF, 0xF, true);
    p = fmaxf(p, __int_as_float(x));
    x = __builtin_amdgcn_update_dpp(0, __float_as_int(p), 0x4E, 0xF, 0xF, true);
    p = fmaxf(p, __int_as_float(x));
    x = __builtin_amdgcn_update_dpp(0, __float_as_int(p), 0x141, 0xF, 0xF, true);
    p = fmaxf(p, __int_as_float(x));
    return p;
}
// pairwise add with lane^8 partner (row_ror:8 within 16-lane rows)
__device__ __forceinline__ float ror8_add(float p) {
    int x = __builtin_amdgcn_update_dpp(0, __float_as_int(p), 0x128, 0xF, 0xF, true);
    return p + __int_as_float(x);
}

// ------- fused prep: deg count + conv_x + conv_w1 + conv_w2 -------

__global__ __launch_bounds__(256) void k_prep(const int* __restrict__ ei,
        int* __restrict__ deg, const float* __restrict__ x,
        unsigned short* __restrict__ A, const float* __restrict__ Wl,
        const float* __restrict__ Wr, unsigned short* __restrict__ Bt,
        const float* __restrict__ W2l, const float* __restrict__ W2r,
        unsigned short* __restrict__ Bt2) {
    int b = blockIdx.x, t = threadIdx.x;
    if (b < NB_COUNT) {
        int e = b * 256 + t;
        if (e >= ET) return;
        int d = (e < N_EDGES) ? ei[N_EDGES + e] : (e - N_EDGES);
        atomicAdd(&deg[d], 1);
    } else if (b < NB_COUNT + NB_CONVX) {
        int idx = (b - NB_COUNT) * 256 + t;       // < N_NODES*64
        int m = idx >> 6, kg = (idx & 63) << 2;
        float4 v = *reinterpret_cast<const float4*>(x + (size_t)m * 256 + kg);
        ushort4 hi = make_ushort4(f2bf(v.x), f2bf(v.y), f2bf(v.z), f2bf(v.w));
        *reinterpret_cast<ushort4*>(A + (size_t)m * 256 + kg) = hi;
    } else if (b < NB_COUNT + NB_CONVX + NB_CONVW) {
        int idx = (b - NB_COUNT - NB_CONVX) * 256 + t;   // < 1024*64
        int n = idx >> 6, kg = (idx & 63) << 2;
        const float* src = (n < 512) ? (Wl + n) : (Wr + (n - 512));
        float v0 = src[(size_t)(kg + 0) * 512];
        float v1 = src[(size_t)(kg + 1) * 512];
        float v2 = src[(size_t)(kg + 2) * 512];
        float v3 = src[(size_t)(kg + 3) * 512];
        ushort4 hi = make_ushort4(f2bf(v0), f2bf(v1), f2bf(v2), f2bf(v3));
        *reinterpret_cast<ushort4*>(Bt + (size_t)n * 256 + kg) = hi;
    } else {
        int idx = (b - NB_COUNT - NB_CONVX - NB_CONVW) * 256 + t;  // < 64*128
        int j = idx >> 7, kg = (idx & 127) << 2;
        const float* src = (j < 32) ? (W2l + j) : (W2r + (j - 32));
        float v0 = src[(size_t)(kg + 0) * 32];
        float v1 = src[(size_t)(kg + 1) * 32];
        float v2 = src[(size_t)(kg + 2) * 32];
        float v3 = src[(size_t)(kg + 3) * 32];
        ushort4 hi = make_ushort4(f2bf(v0), f2bf(v1), f2bf(v2), f2bf(v3));
        *reinterpret_cast<ushort4*>(Bt2 + (size_t)j * 512 + kg) = hi;
    }
}

// ---------------- CSR scan ----------------

__global__ __launch_bounds__(1024) void k_scan(const int* __restrict__ deg,
                                               int* __restrict__ offs) {
    __shared__ int part[1024];
    const int CH = 10;                       // ceil(10000/1024)
    int t = threadIdx.x;
    int base = t * CH;
    int loc[CH];
    int s = 0;
    for (int i = 0; i < CH; ++i) {
        int idx = base + i;
        int v = (idx < N_NODES) ? deg[idx] : 0;
        loc[i] = s; s += v;
    }
    part[t] = s;
    __syncthreads();
    for (int o = 1; o < 1024; o <<= 1) {
        int add = (t >= o) ? part[t - o] : 0;
        __syncthreads();
        part[t] += add;
        __syncthreads();
    }
    int excl = part[t] - s;
    for (int i = 0; i < CH; ++i) {
        int idx = base + i;
        if (idx < N_NODES) offs[idx] = excl + loc[i];
    }
    if (t == 1023) offs[N_NODES] = part[1023];
}

// ---------- fused scatter + layer-1 MFMA GEMM (independent work) ----------
// blocks [0, NB_COUNT): edge scatter.  blocks [NB_COUNT, +632): 128x128 GEMM
// tiles, M=10000 N=1024 K=256 bf16, 4 waves/block.

__global__ __launch_bounds__(256) void k_scm1(const int* __restrict__ ei,
        const int* __restrict__ offs, int* __restrict__ deg,
        int* __restrict__ ssrc, const unsigned short* __restrict__ A,
        const unsigned short* __restrict__ Bt, unsigned short* __restrict__ xl1b,
        unsigned short* __restrict__ xr1b) {
    __shared__ unsigned short As[128 * 40];   // stride 40: 2-way max = free
    __shared__ unsigned short Bs[128 * 40];
    int t = threadIdx.x;
    if (blockIdx.x < NB_COUNT) {
        // ---- scatter (deg doubles as countdown cursor) ----
        int e = blockIdx.x * 256 + t;
        if (e >= ET) return;
        int s, d;
        if (e < N_EDGES) { s = ei[e]; d = ei[N_EDGES + e]; }
        else             { s = d = e - N_EDGES; }
        int pos = offs[d] + atomicAdd(&deg[d], -1) - 1;
        ssrc[pos] = s;
        return;
    }
    int bb = blockIdx.x - NB_COUNT;
    int row0 = (bb % 79) * 128, n0 = (bb / 79) * 128;
    int wave = t >> 6, L = t & 63;
    int wm = wave & 1, wn = wave >> 1;
    int q = L >> 4, rr = L & 15;
    floatx4 acc[4][4];
#pragma unroll
    for (int i = 0; i < 4; ++i)
#pragma unroll
        for (int j = 0; j < 4; ++j) acc[i][j] = (floatx4){0.f, 0.f, 0.f, 0.f};
    int ra = t >> 2,        ka = (t & 3) * 8;
    int rb = (t + 256) >> 2, kb = ((t + 256) & 3) * 8;
    int gma = row0 + ra; gma = (gma < N_NODES) ? gma : (N_NODES - 1);
    int gmb = row0 + rb; gmb = (gmb < N_NODES) ? gmb : (N_NODES - 1);
    for (int kc = 0; kc < 256; kc += 32) {
        __syncthreads();
        *reinterpret_cast<uint4*>(&As[ra * 40 + ka]) =
            *reinterpret_cast<const uint4*>(A + (size_t)gma * 256 + kc + ka);
        *reinterpret_cast<uint4*>(&As[rb * 40 + kb]) =
            *reinterpret_cast<const uint4*>(A + (size_t)gmb * 256 + kc + kb);
        *reinterpret_cast<uint4*>(&Bs[ra * 40 + ka]) =
            *reinterpret_cast<const uint4*>(Bt + (size_t)(n0 + ra) * 256 + kc + ka);
        *reinterpret_cast<uint4*>(&Bs[rb * 40 + kb]) =
            *reinterpret_cast<const uint4*>(Bt + (size_t)(n0 + rb) * 256 + kc + kb);
        __syncthreads();
        short8 af[4], bf[4];
#pragma unroll
        for (int st = 0; st < 4; ++st)
            af[st] = *reinterpret_cast<const short8*>(
                &As[(wm * 64 + st * 16 + rr) * 40 + q * 8]);
#pragma unroll
        for (int st = 0; st < 4; ++st)
            bf[st] = *reinterpret_cast<const short8*>(
                &Bs[(wn * 64 + st * 16 + rr) * 40 + q * 8]);
#pragma unroll
        for (int i = 0; i < 4; ++i)
#pragma unroll
            for (int j = 0; j < 4; ++j)
                acc[i][j] = __builtin_amdgcn_mfma_f32_16x16x32_bf16(
                    af[i], bf[j], acc[i][j], 0, 0, 0);
    }
    // epilogue: C/D layout col=lane&15, row=(lane>>4)*4+reg  [m89/m91]
#pragma unroll
    for (int j = 0; j < 4; ++j) {
        int gc = n0 + wn * 64 + j * 16 + rr;
        unsigned short* dst = (gc < 512) ? xl1b : xr1b;
        int col = (gc < 512) ? gc : (gc - 512);
#pragma unroll
        for (int i = 0; i < 4; ++i)
#pragma unroll
            for (int r = 0; r < 4; ++r) {
                int gr = row0 + wm * 64 + i * 16 + q * 4 + r;
                if (gr < N_NODES)
                    dst[(size_t)gr * 512 + col] = f2bf(acc[i][j][r]);
            }
    }
}

// Fused edge+node layer 1 — 2 waves per node (block = 2 nodes), packed-f32
// math, batched indices (R22), depth-4 row prefetch, LDS cross-wave combine.
__global__ __launch_bounds__(256) void k_node1f(const int* __restrict__ offs,
        const int* __restrict__ ssrc, const unsigned short* __restrict__ xl1b,
        const unsigned short* __restrict__ xr1b, const float* __restrict__ att1,
        const float* __restrict__ b1, unsigned short* __restrict__ h1b) {
    __shared__ float comb[2][64][9];
    int t = threadIdx.x;
    int wave = t >> 6, lane = t & 63;
    int ni = wave >> 1, wv = wave & 1;
    int n = blockIdx.x * 2 + ni;             // grid = 5000 exactly -> n < 10000
    int beg0 = offs[n], d = offs[n + 1] - beg0;
    int half = (d + 1) >> 1;
    int beg = beg0 + (wv ? half : 0);
    int dcnt = wv ? (d - half) : half;       // wv=1 may get 0 edges (d==1)
    floatx2 xrp0, xrp1, xrp2, xrp3;
    floatx2 c1p0, c1p1, c1p2, c1p3;          // 0.6 * att
    floatx2 c2p0, c2p1, c2p2, c2p3;          // 0.4 * att
    float K0;                                 // sum(0.6*att*xr) for this lane
    {
        ushort8_t xru = *reinterpret_cast<const ushort8_t*>(
            xr1b + (size_t)n * 512 + lane * 8);
        union { ushort8_t v; uint4 w; } cv; cv.v = xru;
        xrp0 = unpk(cv.w.x); xrp1 = unpk(cv.w.y);
        xrp2 = unpk(cv.w.z); xrp3 = unpk(cv.w.w);
        const float* atrow = att1 + lane * 8;
        float4 c0 = *reinterpret_cast<const float4*>(atrow);
        float4 c1 = *reinterpret_cast<const float4*>(atrow + 4);
        c1p0 = (floatx2){0.6f * c0.x, 0.6f * c0.y};
        c1p1 = (floatx2){0.6f * c0.z, 0.6f * c0.w};
        c1p2 = (floatx2){0.6f * c1.x, 0.6f * c1.y};
        c1p3 = (floatx2){0.6f * c1.z, 0.6f * c1.w};
        c2p0 = (floatx2){0.4f * c0.x, 0.4f * c0.y};
        c2p1 = (floatx2){0.4f * c0.z, 0.4f * c0.w};
        c2p2 = (floatx2){0.4f * c1.x, 0.4f * c1.y};
        c2p3 = (floatx2){0.4f * c1.z, 0.4f * c1.w};
        K0 = c1p0.x * xrp0.x + c1p0.y * xrp0.y
           + c1p1.x * xrp1.x + c1p1.y * xrp1.y
           + c1p2.x * xrp2.x + c1p2.y * xrp2.y
           + c1p3.x * xrp3.x + c1p3.y * xrp3.y;
    }
    floatx2 k0p = (floatx2){K0, 0.f};
    float l = 0.f;
    floatx2 ac0 = {0.f, 0.f}, ac1 = {0.f, 0.f}, ac2 = {0.f, 0.f}, ac3 = {0.f, 0.f};
    const int* sp = ssrc + beg;
    const char* xlbase = reinterpret_cast<const char*>(xl1b) + lane * 16;
    auto ld_row = [&](int off) -> ushort8_t {
        return *reinterpret_cast<const ushort8_t*>(xlbase + off);
    };
    for (int b0 = 0; b0 < dcnt; b0 += 64) {
        int bn = dcnt - b0; if (bn > 64) bn = 64;
        // one batched index load per 64 edges (clamped; bn >= 1 here)
        int idxv = sp[b0 + ((lane < bn) ? lane : (bn - 1))];
        auto off_at = [&](int k) -> int {
            int kc = (k < bn) ? k : (bn - 1);
            return __shfl(idxv, kc, 64) << 10;   // ds_bpermute: lgkmcnt path
        };
        // per-edge compute; idx >= bn contributes 0 (tail mask)
        auto edge = [&](ushort8_t u, int idx) {
            union { ushort8_t v; uint4 w; } cv; cv.v = u;
            floatx2 xs0 = unpk(cv.w.x), xs1 = unpk(cv.w.y),
                    xs2 = unpk(cv.w.z), xs3 = unpk(cv.w.w);
            floatx2 dd = pk_fma(xs0, c1p0, k0p);     // 0.6at . xs  (+K0)
            dd = pk_fma(xs1, c1p1, dd);
            dd = pk_fma(xs2, c1p2, dd);
            dd = pk_fma(xs3, c1p3, dd);
            floatx2 a0 = pk_add(xs0, xrp0);
            floatx2 a1 = pk_add(xs1, xrp1);
            floatx2 a2 = pk_add(xs2, xrp2);
            floatx2 a3 = pk_add(xs3, xrp3);
            a0.x = fabsf(a0.x); a0.y = fabsf(a0.y);
            a1.x = fabsf(a1.x); a1.y = fabsf(a1.y);
            a2.x = fabsf(a2.x); a2.y = fabsf(a2.y);
            a3.x = fabsf(a3.x); a3.y = fabsf(a3.y);
            dd = pk_fma(a0, c2p0, dd);               // + 0.4at . |xs+xr|
            dd = pk_fma(a1, c2p1, dd);
            dd = pk_fma(a2, c2p2, dd);
            dd = pk_fma(a3, c2p3, dd);
            float p = red8_dpp(dd.x + dd.y);         // alpha for this head
            float w = __expf(fminf(p, 60.f));
            if (idx >= bn) w = 0.f;
            l += w;
            floatx2 wp = (floatx2){w, w};
            ac0 = pk_fma(xs0, wp, ac0);
            ac1 = pk_fma(xs1, wp, ac1);
            ac2 = pk_fma(xs2, wp, ac2);
            ac3 = pk_fma(xs3, wp, ac3);
        };
        ushort8_t u0 = ld_row(off_at(0));
        ushort8_t u1 = ld_row(off_at(1));
        ushort8_t u2 = ld_row(off_at(2));
        ushort8_t u3 = ld_row(off_at(3));
        for (int i = 0; i < bn; i += 4) {
            ushort8_t p0 = ld_row(off_at(i + 4));   // prefetch next block
            ushort8_t p1 = ld_row(off_at(i + 5));
            ushort8_t p2 = ld_row(off_at(i + 6));
            ushort8_t p3 = ld_row(off_at(i + 7));
            edge(u0, i);
            edge(u1, i + 1);
            edge(u2, i + 2);
            edge(u3, i + 3);
            u0 = p0; u1 = p1; u2 = p2; u3 = p3;
        }
    }
    // cross-wave combine (wave wv=1 -> LDS, wv=0 adds + writes out)
    if (wv == 1) {
        float* cb = &comb[ni][lane][0];
        cb[0] = ac0.x; cb[1] = ac0.y; cb[2] = ac1.x; cb[3] = ac1.y;
        cb[4] = ac2.x; cb[5] = ac2.y; cb[6] = ac3.x; cb[7] = ac3.y;
        cb[8] = l;
    }
    __syncthreads();
    if (wv == 0) {
        const float* cb = &comb[ni][lane][0];
        float av0 = ac0.x + cb[0], av1 = ac0.y + cb[1];
        float av2 = ac1.x + cb[2], av3 = ac1.y + cb[3];
        float av4 = ac2.x + cb[4], av5 = ac2.y + cb[5];
        float av6 = ac3.x + cb[6], av7 = ac3.y + cb[7];
        float lt = l + cb[8];
        float inv = 1.f / (lt + 1e-16f);
        const float* brow = b1 + lane * 8;
        float av[8] = {av0, av1, av2, av3, av4, av5, av6, av7};
        ushort8_t vout;
#pragma unroll
        for (int j = 0; j < 8; ++j) {
            float v = av[j] * inv + brow[j];
            v = (v > 0.f) ? v : (__expf(v) - 1.f);  // elu (fast exp)
            vout[j] = f2bf(v);
        }
        *reinterpret_cast<ushort8_t*>(h1b + (size_t)n * 512 + lane * 8) = vout;
    }
}

// ---------------- layer 2: MFMA GEMM ----------------

// M=10000, N=64, K=512 bf16. 64-row tiles, 4 waves (wave = 16 rows).
__global__ __launch_bounds__(256) void k_mfma2(const unsigned short* __restrict__ h1b,
        const unsigned short* __restrict__ Bt2, float* __restrict__ xw2) {
    __shared__ unsigned short Hs[64 * 40];
    __shared__ unsigned short Ws[64 * 40];
    int t = threadIdx.x;
    int wave = t >> 6, L = t & 63;
    int row0 = blockIdx.x * 64;
    int q = L >> 4, rr = L & 15;
    floatx4 acc[4];
#pragma unroll
    for (int j = 0; j < 4; ++j) acc[j] = (floatx4){0.f, 0.f, 0.f, 0.f};
    int ra = t >> 2, ka = (t & 3) * 8;       // 64 rows x 4 chunks = 1/thread
    int gma = row0 + ra; gma = (gma < N_NODES) ? gma : (N_NODES - 1);
    for (int kc = 0; kc < 512; kc += 32) {
        __syncthreads();
        *reinterpret_cast<uint4*>(&Hs[ra * 40 + ka]) =
            *reinterpret_cast<const uint4*>(h1b + (size_t)gma * 512 + kc + ka);
        *reinterpret_cast<uint4*>(&Ws[ra * 40 + ka]) =
            *reinterpret_cast<const uint4*>(Bt2 + (size_t)ra * 512 + kc + ka);
        __syncthreads();
        short8 af = *reinterpret_cast<const short8*>(
            &Hs[(wave * 16 + rr) * 40 + q * 8]);
#pragma unroll
        for (int j = 0; j < 4; ++j) {
            short8 bf = *reinterpret_cast<const short8*>(
                &Ws[(j * 16 + rr) * 40 + q * 8]);
            acc[j] = __builtin_amdgcn_mfma_f32_16x16x32_bf16(af, bf, acc[j], 0, 0, 0);
        }
    }
    // epilogue: col=lane&15, row=(lane>>4)*4+reg
#pragma unroll
    for (int j = 0; j < 4; ++j) {
        int gc = j * 16 + rr;
#pragma unroll
        for (int r = 0; r < 4; ++r) {
            int gr = row0 + wave * 16 + q * 4 + r;
            if (gr < N_NODES) xw2[(size_t)gr * 64 + gc] = acc[j][r];
        }
    }
}

// Fused edge+node layer 2 + log_softmax: block = 4 nodes, wave = node,
// barrier-free. R23: batched index loads (as node1f) + depth-2 row pipeline;
// only row gathers remain on the vmcnt path. (xw2 is 2.5 MB, L2-hot.)
__global__ __launch_bounds__(256) void k_node2f(const int* __restrict__ offs,
        const int* __restrict__ ssrc, const float* __restrict__ xw2,
        const float* __restrict__ att2, const float* __restrict__ b2,
        float* __restrict__ out) {
    int t = threadIdx.x;
    int wave = t >> 6, lane = t & 63;
    int n = blockIdx.x * 4 + wave;
    if (n >= N_NODES) return;
    int ej = lane >> 3;
    int cg = lane & 7;
    int beg = offs[n], dcnt = offs[n + 1] - beg;
    float4 xr = *reinterpret_cast<const float4*>(
                    xw2 + (size_t)n * 64 + 32 + cg * 4);
    float4 at = *reinterpret_cast<const float4*>(att2 + cg * 4);
    float l = 0.f;
    float4 ac = {0.f, 0.f, 0.f, 0.f};
    const int* sp = ssrc + beg;
    const char* xwbase = reinterpret_cast<const char*>(xw2) + cg * 16;
    auto ld_row = [&](int off) -> float4 {
        return *reinterpret_cast<const float4*>(xwbase + off);
    };
    for (int b0 = 0; b0 < dcnt; b0 += 64) {
        int bn = dcnt - b0; if (bn > 64) bn = 64;
        int idxv = sp[b0 + ((lane < bn) ? lane : (bn - 1))];
        auto off_at = [&](int k) -> int {
            int kc = (k < bn) ? k : (bn - 1);
            return __shfl(idxv, kc, 64) << 8;    // ds_bpermute: lgkmcnt path
        };
        float4 uA  = ld_row(off_at(ej));
        float4 uB  = ld_row(off_at(8 + ej));
        float4 uA1 = ld_row(off_at(16 + ej));
        float4 uB1 = ld_row(off_at(24 + ej));
        for (int base = 0; base < bn; base += 16) {
            float4 uA2 = ld_row(off_at(base + 32 + ej));
            float4 uB2 = ld_row(off_at(base + 40 + ej));
            float pA0 = lrelu(uA.x + xr.x) * at.x + lrelu(uA.z + xr.z) * at.z;
            float pA1 = lrelu(uA.y + xr.y) * at.y + lrelu(uA.w + xr.w) * at.w;
            float pB0 = lrelu(uB.x + xr.x) * at.x + lrelu(uB.z + xr.z) * at.z;
            float pB1 = lrelu(uB.y + xr.y) * at.y + lrelu(uB.w + xr.w) * at.w;
            float pA = red8_dpp(pA0 + pA1);
            float pB = red8_dpp(pB0 + pB1);
            if (base + ej >= bn)     pA = -1e30f;
            if (base + 8 + ej >= bn) pB = -1e30f;
            float wA = __expf(fminf(pA, 60.f));
            float wB = __expf(fminf(pB, 60.f));
            l += wA + wB;
            ac.x += wA * uA.x + wB * uB.x;
            ac.y += wA * uA.y + wB * uB.y;
            ac.z += wA * uA.z + wB * uB.z;
            ac.w += wA * uA.w + wB * uB.w;
            uA = uA1; uB = uB1; uA1 = uA2; uB1 = uB2;
        }
    }
    l = ror8_add(l); l += __shfl_xor(l, 16); l += __shfl_xor(l, 32);
    ac.x = ror8_add(ac.x); ac.x += __shfl_xor(ac.x, 16); ac.x += __shfl_xor(ac.x, 32);
    ac.y = ror8_add(ac.y); ac.y += __shfl_xor(ac.y, 16); ac.y += __shfl_xor(ac.y, 32);
    ac.z = ror8_add(ac.z); ac.z += __shfl_xor(ac.z, 16); ac.z += __shfl_xor(ac.z, 32);
    ac.w = ror8_add(ac.w); ac.w += __shfl_xor(ac.w, 16); ac.w += __shfl_xor(ac.w, 32);
    float inv = 1.f / (l + 1e-16f);
    float4 bb = *reinterpret_cast<const float4*>(b2 + cg * 4);
    float4 v;
    v.x = ac.x * inv + bb.x; v.y = ac.y * inv + bb.y;
    v.z = ac.z * inv + bb.z; v.w = ac.w * inv + bb.w;
    // log_softmax over 32 channels (8-lane DPP; ej groups identical)
    float mx = red8max_dpp(fmaxf(fmaxf(v.x, v.y), fmaxf(v.z, v.w)));
    float se = red8_dpp(__expf(v.x - mx) + __expf(v.y - mx)
                      + __expf(v.z - mx) + __expf(v.w - mx));
    float ls = __logf(se);
    v.x = v.x - mx - ls; v.y = v.y - mx - ls;
    v.z = v.z - mx - ls; v.w = v.w - mx - ls;
    if (ej == 0)
        *reinterpret_cast<float4*>(out + (size_t)n * 32 + cg * 4) = v;
}

// ---------------- launch ----------------

extern "C" void kernel_launch(void* const* d_in, const int* in_sizes, int n_in,
                              void* d_out, int out_size, void* d_ws, size_t ws_size,
                              hipStream_t stream) {
    (void)in_sizes; (void)n_in; (void)out_size; (void)ws_size;
    const float* x    = (const float*)d_in[0];
    const int*   ei   = (const int*)d_in[1];
    const float* W1l  = (const float*)d_in[2];
    const float* W1r  = (const float*)d_in[3];
    const float* att1 = (const float*)d_in[4];
    const float* b1   = (const float*)d_in[5];
    const float* W2l  = (const float*)d_in[6];
    const float* W2r  = (const float*)d_in[7];
    const float* att2 = (const float*)d_in[8];
    const float* b2   = (const float*)d_in[9];
    float* outp = (float*)d_out;

    char* ws = (char*)d_ws;
    size_t o = 0;
    auto alloc = [&](size_t bytes) {
        char* p = ws + o;
        o = (o + bytes + 255) & ~(size_t)255;
        return p;
    };
    unsigned short* xl1b = (unsigned short*)alloc((size_t)N_NODES * 512 * 2);
    unsigned short* xr1b = (unsigned short*)alloc((size_t)N_NODES * 512 * 2);
    unsigned short* h1b  = (unsigned short*)alloc((size_t)N_NODES * 512 * 2);
    float* xw2    = (float*)alloc((size_t)N_NODES * 64 * 4);
    unsigned short* Abf = (unsigned short*)alloc((size_t)N_NODES * 256 * 2);
    unsigned short* Bbf = (unsigned short*)alloc((size_t)1024 * 256 * 2);
    unsigned short* Bt2 = (unsigned short*)alloc((size_t)64 * 512 * 2);
    int*   deg    = (int*)alloc((size_t)N_NODES * 4);
    int*   offs   = (int*)alloc((size_t)(N_NODES + 1) * 4);
    int*   ssrc   = (int*)alloc((size_t)ET * 4);

    hipMemsetAsync(deg, 0, (size_t)N_NODES * 4, stream);

    k_prep   <<<NB_COUNT + NB_CONVX + NB_CONVW + NB_CONVW2, 256, 0, stream>>>(
                 ei, deg, x, Abf, W1l, W1r, Bbf, W2l, W2r, Bt2);
    k_scan   <<<1,                    1024, 0, stream>>>(deg, offs);
    k_scm1   <<<NB_COUNT + NB_M1,      256, 0, stream>>>(ei, offs, deg, ssrc,
                                                         Abf, Bbf, xl1b, xr1b);
    k_node1f <<<N_NODES / 2,           256, 0, stream>>>(offs, ssrc, xl1b, xr1b, att1, b1, h1b);
    k_mfma2  <<<(N_NODES + 63) / 64,   256, 0, stream>>>(h1b, Bt2, xw2);
    k_node2f <<<(N_NODES + 3) / 4,     256, 0, stream>>>(offs, ssrc, xw2, att2, b2, outp);
}